// Round 2
// baseline (87.687 us; speedup 1.0000x reference)
//
#include <hip/hip_runtime.h>
#include <cmath>

#define T_STEPS 384
#define CH 64
#define NCH 6
#define WREP_STRIDE 392   // 384+8: bank map (8r - lane) mod 32 is conflict-free

__device__ __forceinline__ float readlane_f(float v, int l) {
    return __int_as_float(__builtin_amdgcn_readlane(__float_as_int(v), l));
}

// One wave per neuron; lane l owns step cb+l of the current 64-step chunk.
// u_l = c2 + c3*I_l - mem_l. Far field: blocked Toeplitz matvec with per-lane
// ds_read_b128 weights (4-copy shifted reversed table for alignment) and
// uniform-broadcast delta float4s. Near field: forward scatter; the per-step
// weight comes from an 8-deep register ring prefetched from LDS 8 steps
// ahead (period-64 sequence -> ring is seamless across chunks), so no LDS
// latency sits in the serial chain.
__global__ __launch_bounds__(64, 2)
void flif_kernel(const float* __restrict__ I_old, const float* __restrict__ W,
                 float* __restrict__ out, float c1, float c2, float c3, int Stot)
{
    const int s    = blockIdx.x;
    const int lane = threadIdx.x;

    __shared__ __align__(16) float wrep[4 * WREP_STRIDE]; // wrep[r][k] = wr[384-(k+r)]
    __shared__ float ltab[2 * CH];                        // ltab[63+a] = wr[a], else 0
    __shared__ __align__(16) float dbuf[T_STEPS];         // delta history

    const float* Irow = I_old + (size_t)s * T_STEPS;
    float Inext = Irow[lane];

    // near-field table
    ltab[lane] = 0.0f;
    ltab[64 + lane] = (lane < 63) ? W[4998 - lane] : 0.0f;   // ltab[63+a]=wr[a]=W[4999-a]
    // far-field replicated reversed table: rt[i] = wr[384-i] = W[4615+i]
    #pragma unroll
    for (int r2 = 0; r2 < 4; ++r2) {
        for (int k = lane; k < WREP_STRIDE; k += 64) {
            const int i = k + r2;
            wrep[r2 * WREP_STRIDE + k] = (i >= 1 && i <= 383) ? W[4615 + i] : 0.0f;
        }
    }
    __syncthreads();

    float* out_spk = out + (size_t)s * T_STEPS;
    float* out_trc = out + (size_t)Stot * T_STEPS + (size_t)s * T_STEPS;

    // per-lane base into the replicated table: copy rsel, 16B-aligned
    const int rsel = (-lane) & 3;
    const float* wlane = wrep + rsel * WREP_STRIDE + (384 - lane - rsel);

    float V = 0.0f;    // uniform across lanes at all times

    // weight ring: before step i, wpre[i&7] == ltab[lane+63-i] == wr[lane-i]
    float wpre[8];
    #pragma unroll
    for (int k = 0; k < 8; ++k) wpre[k] = ltab[lane + 63 - k];

    for (int c = 0; c < NCH; ++c) {
        const int cb = c * CH;
        const float Ic = Inext;
        if (c + 1 < NCH) Inext = Irow[cb + CH + lane];

        // ---- far field: acc = sum_{j<cb} delta_j * wr[(cb+lane)-j] ----
        float acc = 0.0f;
        const float* wp = wlane - cb;
        #pragma unroll 4
        for (int j = 0; j < cb; j += 4) {
            const float4 d4 = *reinterpret_cast<const float4*>(&dbuf[j]);   // uniform -> broadcast
            const float4 w4 = *reinterpret_cast<const float4*>(wp + j);     // per-lane b128
            acc = fmaf(d4.x, w4.x, acc);
            acc = fmaf(d4.y, w4.y, acc);
            acc = fmaf(d4.z, w4.z, acc);
            acc = fmaf(d4.w, w4.w, acc);
        }

        float u = fmaf(c3, Ic, c2) - acc;
        const float Vs = V;
        float tc = 0.0f;

        auto step = [&](int i) {
            const float w = wpre[i & 7];                         // wr[lane-i], prefetched
            wpre[i & 7] = ltab[lane + 63 - ((i + 8) & 63)];      // refill for step i+8
            const float t  = readlane_f(u, i);                   // scalar broadcast
            const float r  = (V > -50.0f) ? 20.0f : 0.0f;        // spike uses PREVIOUS V
            const float V2 = fmaf(c1, V, t);
            const float Vn = V2 - r;
            const float d  = Vn - V;
            u = fmaf(-w, d, u);                                  // forward-scatter delta
            if (lane == i) tc = Vn;
            V = Vn;
        };

        if (c == 0) {
            {   // step 0: V_prev=0 -> spike, V_pre=-70, V_new=-90; delta masked out
                wpre[0] = ltab[lane + 63 - 8];                   // keep ring moving
                V = -90.0f;
                if (lane == 0) tc = V;
            }
            {   // step 1: V1 rule, no memory term; scatter delta_1 with wr[lane-1]
                const float w = wpre[1];
                wpre[1] = ltab[lane + 63 - 9];
                const float I1 = readlane_f(Ic, 1);
                const float V1 = fmaf(0.005f, (I1 / 0.025f) - V, V);
                const float r  = (V > -50.0f) ? 20.0f : 0.0f;    // V=-90 -> no reset
                const float Vn = V1 - r;
                const float d  = Vn - V;
                u = fmaf(-w, d, u);
                if (lane == 1) tc = Vn;
                V = Vn;
            }
            #pragma unroll
            for (int i = 2; i < CH; ++i) step(i);
        } else {
            #pragma unroll
            for (int i = 0; i < CH; ++i) step(i);
        }

        // ---- chunk epilogue: reconstruct prev-V per lane -> spike, delta ----
        float prev = __shfl_up(tc, 1);
        if (lane == 0) prev = Vs;
        const float spk = (prev > -50.0f) ? 1.0f : 0.0f;
        float d = tc - prev;
        if (c == 0 && lane == 0) d = 0.0f;                       // delta_0 excluded
        dbuf[cb + lane] = d;
        out_spk[cb + lane] = spk;
        out_trc[cb + lane] = tc;
        __syncthreads();
    }
}

extern "C" void kernel_launch(void* const* d_in, const int* in_sizes, int n_in,
                              void* d_out, int out_size, void* d_ws, size_t ws_size,
                              hipStream_t stream) {
    const float* I = (const float*)d_in[0];
    const float* W = (const float*)d_in[1];
    float* out = (float*)d_out;
    const int S = in_sizes[0] / T_STEPS;   // 2048

    const double COEF = std::pow(0.1, 0.15) * std::tgamma(1.85) / 0.5;
    const float c3 = (float)COEF;                      // COEF
    const float c1 = (float)(1.0 - COEF * 0.025);      // 1 - COEF*GL
    const float c2 = (float)(COEF * 0.025 * -70.0);    // COEF*GL*VL

    flif_kernel<<<S, 64, 0, stream>>>(I, W, out, c1, c2, c3, S);
}

// Round 3
// 86.852 us; speedup vs baseline: 1.0096x; 1.0096x over previous
//
#include <hip/hip_runtime.h>
#include <cmath>

#define T_STEPS 384
#define CH 64
#define NCH 6
#define WREP_STRIDE 392   // 384+8; per-lane b128 reads spread uniformly over banks

__device__ __forceinline__ float readlane_f(float v, int l) {
    return __int_as_float(__builtin_amdgcn_readlane(__float_as_int(v), l));
}

// One wave per neuron; lane l owns step cb+l of the current 64-step chunk.
// u[l] = c2 + c3*I_l - mem_l, built from a far-field Toeplitz matvec (LDS,
// chunk prologue) plus an in-chunk forward scatter of each step's delta.
// Serial chain is shortened by 1-step lookahead:
//   t_{i} = readlane(u_{i-2}, i) - wr[1]*d_{i-1}
// so the cross-step dependency is only fma+add (~8 cyc); the readlane,
// scatter, V/b updates, and tc capture all have >= 1 step of slack.
// Near-field scatter weights live in 64 registers (period-64, chunk
// invariant): ZERO per-step LDS traffic.
__global__ __launch_bounds__(64, 2)
void flif_kernel(const float* __restrict__ I_old, const float* __restrict__ W,
                 float* __restrict__ out, float cm1, float c2, float c3, int Stot)
{
    const int s    = blockIdx.x;
    const int lane = threadIdx.x;

    __shared__ __align__(16) float wrep[4 * WREP_STRIDE]; // wrep[r][k] = wr[384-(k+r)]
    __shared__ __align__(16) float lrep[4 * 128];         // lrep[r][k] = ltab[k+r]
    __shared__ __align__(16) float dbuf[T_STEPS];         // delta history

    const float* Irow = I_old + (size_t)s * T_STEPS;
    float Inext = Irow[lane];

    // ltab[x] = wr[x-63] = W[5062-x] for x in [64,126], else 0  (wr[a]=W[4999-a])
    // rt[i]   = wr[384-i] = W[4615+i] for i in [1,383], else 0
    #pragma unroll
    for (int r = 0; r < 4; ++r) {
        for (int k = lane; k < WREP_STRIDE; k += 64) {
            const int i = k + r;
            wrep[r * WREP_STRIDE + k] = (i >= 1 && i <= 383) ? W[4615 + i] : 0.0f;
        }
        for (int k = lane; k < 128; k += 64) {
            const int x = k + r;
            lrep[r * 128 + k] = (x >= 64 && x <= 126) ? W[5062 - x] : 0.0f;
        }
    }
    __syncthreads();

    // near-field scatter window in REGISTERS: wloc[i] = wr[lane-i] (0 if lane<=i)
    // loaded as 16 aligned b128 (base = lane+60-i0 has base&3 == lane&3)
    float wloc[64];
    {
        const int r = lane & 3;
        const float* lp = lrep + r * 128 - r;             // lp[x] == ltab[x]
        #pragma unroll
        for (int i0 = 0; i0 < 64; i0 += 4) {
            const float4 f = *reinterpret_cast<const float4*>(lp + (lane + 60 - i0));
            wloc[i0 + 0] = f.w; wloc[i0 + 1] = f.z;
            wloc[i0 + 2] = f.y; wloc[i0 + 3] = f.x;
        }
    }

    float* out_spk = out + (size_t)s * T_STEPS;
    float* out_trc = out + (size_t)Stot * T_STEPS + (size_t)s * T_STEPS;

    const int rsel = (-lane) & 3;
    const float* wlane = wrep + rsel * WREP_STRIDE + (384 - lane - rsel);

    const float wr1n = -W[4998];          // -wr[1]; loop-invariant, lives in a VGPR

    float V = 0.0f, d = 0.0f, b = 0.0f, P = 0.0f;

    for (int c = 0; c < NCH; ++c) {
        const int cb = c * CH;
        const float Ic = Inext;
        if (c + 1 < NCH) Inext = Irow[cb + CH + lane];

        // ---- far field: acc = sum_{j<cb} delta_j * wr[(cb+lane)-j] ----
        float acc = 0.0f;
        const float* wp = wlane - cb;
        #pragma unroll 4
        for (int j = 0; j < cb; j += 4) {
            const float4 d4 = *reinterpret_cast<const float4*>(&dbuf[j]); // uniform -> broadcast
            const float4 w4 = *reinterpret_cast<const float4*>(wp + j);   // per-lane b128
            acc = fmaf(d4.x, w4.x, acc);
            acc = fmaf(d4.y, w4.y, acc);
            acc = fmaf(d4.z, w4.z, acc);
            acc = fmaf(d4.w, w4.w, acc);
        }

        float u = fmaf(c3, Ic, c2) - acc;
        const float Vs = V;
        float tc = 0.0f;

        // steady-state step: chain is t=fma(wr1n,d,P); d=t+b. Everything else slack.
        auto body = [&](int i) {
            const float t = fmaf(wr1n, d, P);            // t_i (uniform)
            d = t + b;                                   // d_i (uniform)   [chain]
            P = readlane_f(u, (i + 1) & 63);             // u_{i-1}[i+1], pre-scatter
            V = V + d;                                   // V_i
            const float rv = (V > -50.0f) ? -20.0f : 0.0f;
            b = fmaf(cm1, V, rv);                        // b_{i+1} = (c1-1)V_i - r_{i+1}
            u = fmaf(-wloc[i], d, u);                    // scatter d_i forward
            tc = (lane == i) ? V : tc;                   // capture trace
        };

        if (c == 0) {
            // step 0: V_prev=0 -> spike, V_pre=-70, V_new=-90; delta masked out
            V = -90.0f;
            if (lane == 0) tc = V;
            // step 1: V1 rule (no memory); V=-90 -> no reset
            const float I1 = readlane_f(Ic, 1);
            const float V1 = fmaf(0.005f, (I1 / 0.025f) - V, V);
            const float d1 = V1 - V;
            P = readlane_f(u, 2);                        // ubase[2] (d0 == 0)
            u = fmaf(-wloc[1], d1, u);                   // scatter d_1
            if (lane == 1) tc = V1;
            V = V1;
            d = d1;
            const float rv = (V > -50.0f) ? -20.0f : 0.0f;
            b = fmaf(cm1, V, rv);                        // b_2
            #pragma unroll
            for (int i = 2; i < CH; ++i) body(i);
        } else {
            d = 0.0f;                                    // wr[1]*d_{cb-1} already in far field
            P = readlane_f(u, 0);                        // t_0 = ubase[0]
            // V, b carry across the chunk boundary
            #pragma unroll
            for (int i = 0; i < CH; ++i) body(i);
        }

        // ---- chunk epilogue: reconstruct prev-V per lane -> spike, delta ----
        float prev = __shfl_up(tc, 1);
        if (lane == 0) prev = Vs;
        const float spk = (prev > -50.0f) ? 1.0f : 0.0f;
        float dd = tc - prev;
        if (c == 0 && lane == 0) dd = 0.0f;              // delta_0 excluded by reference
        dbuf[cb + lane] = dd;
        out_spk[cb + lane] = spk;
        out_trc[cb + lane] = tc;
        __syncthreads();
    }
}

extern "C" void kernel_launch(void* const* d_in, const int* in_sizes, int n_in,
                              void* d_out, int out_size, void* d_ws, size_t ws_size,
                              hipStream_t stream) {
    const float* I = (const float*)d_in[0];
    const float* W = (const float*)d_in[1];
    float* out = (float*)d_out;
    const int S = in_sizes[0] / T_STEPS;   // 2048

    const double COEF = std::pow(0.1, 0.15) * std::tgamma(1.85) / 0.5;
    const float c3  = (float)COEF;                     // COEF
    const float cm1 = (float)(-COEF * 0.025);          // c1 - 1 = -COEF*GL
    const float c2  = (float)(COEF * 0.025 * -70.0);   // COEF*GL*VL

    flif_kernel<<<S, 64, 0, stream>>>(I, W, out, cm1, c2, c3, S);
}

// Round 4
// 85.301 us; speedup vs baseline: 1.0280x; 1.0182x over previous
//
#include <hip/hip_runtime.h>
#include <cmath>

#define T_STEPS 384
#define CH 64
#define NCH 6
#define WS 392   // replicated-table stride; 392 % 32 == 8 -> uniform bank spread

__device__ __forceinline__ float readlane_f(float v, int l) {
    return __int_as_float(__builtin_amdgcn_readlane(__float_as_int(v), l));
}

// One wave per neuron; lane l owns step cb+l of the current 64-step chunk.
// Far field: blocked Toeplitz matvec, j ascending (bit-identical order to the
// previous kernel). Weight windows for chunk-distance g=1,2 live in REGISTERS
// (serve 9 of 15 block passes); g>=3 windows come from a 4-way shifted LDS
// replica via per-lane b128. Deltas are uniform-address b128 broadcasts with
// immediate offsets. Near field: forward scatter with register window wloc.
// Step recurrence uses 1-step lookahead; chain = fma+add. No __syncthreads in
// the main loop (single wave per block, LDS is program-ordered within a wave).
__global__ __launch_bounds__(64, 2)
void flif_kernel(const float* __restrict__ I_old, const float* __restrict__ W,
                 float* __restrict__ out, float cm1, float c2, float c3, int Stot)
{
    const int s    = blockIdx.x;
    const int lane = threadIdx.x;

    __shared__ __align__(16) float wrep[4 * WS];    // wrep[r][k] = rt[k+r], rt[i]=wr[384-i]
    __shared__ __align__(16) float lrep[4 * 128];   // lrep[r][k] = ltab[k+r], ltab[x]=wr[x-63]
    __shared__ __align__(16) float dbuf[T_STEPS];   // delta history

    const float* Irow = I_old + (size_t)s * T_STEPS;
    float Inext = Irow[lane];

    #pragma unroll
    for (int r = 0; r < 4; ++r) {
        for (int k = lane; k < WS; k += 64) {
            const int i = k + r;
            wrep[r * WS + k] = (i >= 1 && i <= 383) ? W[4615 + i] : 0.0f;   // rt[i]=wr[384-i]=W[4615+i]
        }
        for (int k = lane; k < 128; k += 64) {
            const int x = k + r;
            lrep[r * 128 + k] = (x >= 64 && x <= 126) ? W[5062 - x] : 0.0f; // ltab[x]=wr[x-63]
        }
    }
    __syncthreads();

    // near-field scatter window in registers: wloc[i] = wr[lane-i] (0 if lane<=i)
    float wloc[64];
    {
        const int r = lane & 3;
        const float* lp = lrep + r * 128 - r;             // lp[x] == ltab[x]
        #pragma unroll
        for (int i0 = 0; i0 < 64; i0 += 4) {
            const float4 f = *reinterpret_cast<const float4*>(lp + (lane + 60 - i0));
            wloc[i0 + 0] = f.w; wloc[i0 + 1] = f.z;
            wloc[i0 + 2] = f.y; wloc[i0 + 3] = f.x;
        }
    }

    // far-field per-lane base: wl[C + k] = rt[C - lane + k]  (16B-aligned for C%4==0)
    const int rsel = (-lane) & 3;
    const float* wl = wrep + rsel * WS - lane - rsel;

    // register weight windows for chunk distance 1 and 2:
    // wgt1[l'] = wr[64+lane-l'] = rt[320-lane+l'],  wgt2[l'] = wr[128+lane-l'] = rt[256-lane+l']
    float wgt1[64], wgt2[64];
    #pragma unroll
    for (int k = 0; k < 64; k += 4) {
        const float4 f1 = *reinterpret_cast<const float4*>(wl + 320 + k);
        wgt1[k] = f1.x; wgt1[k + 1] = f1.y; wgt1[k + 2] = f1.z; wgt1[k + 3] = f1.w;
        const float4 f2 = *reinterpret_cast<const float4*>(wl + 256 + k);
        wgt2[k] = f2.x; wgt2[k + 1] = f2.y; wgt2[k + 2] = f2.z; wgt2[k + 3] = f2.w;
    }

    float* out_spk = out + (size_t)s * T_STEPS;
    float* out_trc = out + (size_t)Stot * T_STEPS + (size_t)s * T_STEPS;

    const float wr1n = -W[4998];          // -wr[1]

    float V = 0.0f, d = 0.0f, b = 0.0f, P = 0.0f;

    for (int c = 0; c < NCH; ++c) {
        const int cb = c * CH;
        const float Ic = Inext;
        if (c + 1 < NCH) Inext = Irow[cb + CH + lane];

        // ---- far field: acc = sum_{j<cb} delta_j * wr[(cb+lane)-j], j ascending ----
        float acc = 0.0f;
        for (int cp = 0; cp < c; ++cp) {            // cp ascending == j ascending
            const int g = c - cp;
            const float* dp = dbuf + cp * CH;
            if (g == 1) {
                #pragma unroll
                for (int k = 0; k < 64; k += 4) {
                    const float4 d4 = *reinterpret_cast<const float4*>(dp + k);  // broadcast
                    acc = fmaf(d4.x, wgt1[k],     acc);
                    acc = fmaf(d4.y, wgt1[k + 1], acc);
                    acc = fmaf(d4.z, wgt1[k + 2], acc);
                    acc = fmaf(d4.w, wgt1[k + 3], acc);
                }
            } else if (g == 2) {
                #pragma unroll
                for (int k = 0; k < 64; k += 4) {
                    const float4 d4 = *reinterpret_cast<const float4*>(dp + k);
                    acc = fmaf(d4.x, wgt2[k],     acc);
                    acc = fmaf(d4.y, wgt2[k + 1], acc);
                    acc = fmaf(d4.z, wgt2[k + 2], acc);
                    acc = fmaf(d4.w, wgt2[k + 3], acc);
                }
            } else {
                const float* wp = wl + (384 - 64 * g);       // wp[k] = wr[64g+lane-k]... via rt
                #pragma unroll
                for (int k = 0; k < 64; k += 4) {
                    const float4 d4 = *reinterpret_cast<const float4*>(dp + k);  // broadcast
                    const float4 w4 = *reinterpret_cast<const float4*>(wp + k);  // per-lane b128
                    acc = fmaf(d4.x, w4.x, acc);
                    acc = fmaf(d4.y, w4.y, acc);
                    acc = fmaf(d4.z, w4.z, acc);
                    acc = fmaf(d4.w, w4.w, acc);
                }
            }
        }

        float u = fmaf(c3, Ic, c2) - acc;
        const float Vs = V;
        float tc = 0.0f;

        // steady-state step: chain is t=fma(wr1n,d,P); d=t+b. Everything else slack.
        auto body = [&](int i) {
            const float t = fmaf(wr1n, d, P);            // t_i (uniform)
            d = t + b;                                   // d_i (uniform)   [chain]
            P = readlane_f(u, (i + 1) & 63);             // u_{i-1}[i+1], pre-scatter
            V = V + d;                                   // V_i
            const float rv = (V > -50.0f) ? -20.0f : 0.0f;
            b = fmaf(cm1, V, rv);                        // b_{i+1}
            u = fmaf(-wloc[i], d, u);                    // scatter d_i forward
            tc = (lane == i) ? V : tc;                   // capture trace
        };

        if (c == 0) {
            // step 0: V_prev=0 -> spike, V_pre=-70, V_new=-90; delta masked out
            V = -90.0f;
            if (lane == 0) tc = V;
            // step 1: V1 rule (no memory); V=-90 -> no reset
            const float I1 = readlane_f(Ic, 1);
            const float V1 = fmaf(0.005f, (I1 / 0.025f) - V, V);
            const float d1 = V1 - V;
            P = readlane_f(u, 2);
            u = fmaf(-wloc[1], d1, u);
            if (lane == 1) tc = V1;
            V = V1;
            d = d1;
            const float rv = (V > -50.0f) ? -20.0f : 0.0f;
            b = fmaf(cm1, V, rv);
            #pragma unroll
            for (int i = 2; i < CH; ++i) body(i);
        } else {
            d = 0.0f;                                    // wr[1]*d_{cb-1} already in far field
            P = readlane_f(u, 0);
            #pragma unroll
            for (int i = 0; i < CH; ++i) body(i);
        }

        // ---- chunk epilogue: reconstruct prev-V per lane -> spike, delta ----
        float prev = __shfl_up(tc, 1);
        if (lane == 0) prev = Vs;
        const float spk = (prev > -50.0f) ? 1.0f : 0.0f;
        float dd = tc - prev;
        if (c == 0 && lane == 0) dd = 0.0f;              // delta_0 excluded by reference
        dbuf[cb + lane] = dd;                            // wave-local, program-ordered
        out_spk[cb + lane] = spk;
        out_trc[cb + lane] = tc;
    }
}

extern "C" void kernel_launch(void* const* d_in, const int* in_sizes, int n_in,
                              void* d_out, int out_size, void* d_ws, size_t ws_size,
                              hipStream_t stream) {
    const float* I = (const float*)d_in[0];
    const float* W = (const float*)d_in[1];
    float* out = (float*)d_out;
    const int S = in_sizes[0] / T_STEPS;   // 2048

    const double COEF = std::pow(0.1, 0.15) * std::tgamma(1.85) / 0.5;
    const float c3  = (float)COEF;                     // COEF
    const float cm1 = (float)(-COEF * 0.025);          // c1 - 1 = -COEF*GL
    const float c2  = (float)(COEF * 0.025 * -70.0);   // COEF*GL*VL

    flif_kernel<<<S, 64, 0, stream>>>(I, W, out, cm1, c2, c3, S);
}